// Round 15
// baseline (76.203 us; speedup 1.0000x reference)
//
#include <hip/hip_runtime.h>
#include <hip/hip_fp8.h>
#include <stdint.h>

#define N_CLS 8192
#define FEAT  512                           // elements; fp8 -> 512 B per row
#define BATCH 1024
#define NTI   32                            // 256-row tiles
#define NTJ   64                            // 128-col tiles
#define NPAIR 1056                          // #{(i,j): j in [2i, 64)}
#define NFULL 1024                          // pairs done by full kernel (8*128)
#define NREMP 32                            // pairs done by rem kernel (x4 quarters)
#define NSLOT 8                             // FEAT/64 (K=64 per slot)
#define SLOTB 24576                         // full: A 256*64 + B 128*64
#define SLOTB_R 12288                       // rem:  A 64*64  + B 128*64

typedef __attribute__((ext_vector_type(4))) float f32x4;
typedef __attribute__((ext_vector_type(2))) long longx2;

__device__ inline unsigned char f2fp8(float x) {
    __hip_fp8_e4m3 q(x);                    // OCP e4m3 (gfx950), HW convert
    return q.__x;
}

// ---------------- Kernel 1: sequential EMA per label -> fp8 protos ---------
// float4 loads, packed 8-B fp8 stores; 1-deep prefetch of next matched
// sample's feature vector (loads are independent of the EMA chain).
__global__ __launch_bounds__(256) void ema_kernel(
    const float* __restrict__ features, const int* __restrict__ labels,
    const float* __restrict__ protos,
    unsigned char* __restrict__ Phi8, float* __restrict__ rowsum,
    int* __restrict__ done) {
    const int row  = blockIdx.x * 4 + (threadIdx.x >> 6);
    const int lane = threadIdx.x & 63;
    if (lane == 0) rowsum[row] = 0.f;
    if (blockIdx.x == 0 && threadIdx.x == 0) *done = 0;

    f32x4 p0 = *(const f32x4*)&protos[(size_t)row * FEAT + lane * 8];
    f32x4 p1 = *(const f32x4*)&protos[(size_t)row * FEAT + lane * 8 + 4];

    for (int c = 0; c < BATCH / 64; ++c) {
        int lab = labels[c * 64 + lane];
        unsigned long long m = __ballot(lab == row);
        if (!m) continue;
        int s = c * 64 + __builtin_ctzll(m);
        f32x4 f0 = *(const f32x4*)&features[(size_t)s * FEAT + lane * 8];
        f32x4 f1 = *(const f32x4*)&features[(size_t)s * FEAT + lane * 8 + 4];
        while (true) {
            m &= m - 1;
            f32x4 cf0 = f0, cf1 = f1;
            if (m) {                        // prefetch next match
                int s2 = c * 64 + __builtin_ctzll(m);
                f0 = *(const f32x4*)&features[(size_t)s2 * FEAT + lane * 8];
                f1 = *(const f32x4*)&features[(size_t)s2 * FEAT + lane * 8 + 4];
            }
            p0 = p0 * 0.95f + cf0 * 0.05f;
            p1 = p1 * 0.95f + cf1 * 0.05f;
            float ss = p0[0]*p0[0] + p0[1]*p0[1] + p0[2]*p0[2] + p0[3]*p0[3]
                     + p1[0]*p1[0] + p1[1]*p1[1] + p1[2]*p1[2] + p1[3]*p1[3];
            #pragma unroll
            for (int off = 32; off; off >>= 1) ss += __shfl_xor(ss, off);
            float inv = 1.0f / fmaxf(sqrtf(ss), 1e-12f);
            p0 *= inv; p1 *= inv;
            if (!m) break;
        }
    }
    unsigned long long packed = 0;
    #pragma unroll
    for (int jj = 0; jj < 4; ++jj)
        packed |= (unsigned long long)f2fp8(p0[jj]) << (8 * jj);
    #pragma unroll
    for (int jj = 0; jj < 4; ++jj)
        packed |= (unsigned long long)f2fp8(p1[jj]) << (8 * (jj + 4));
    *(unsigned long long*)&Phi8[(size_t)row * FEAT + lane * 8] = packed;
}

// ---------------- Kernel 2a: 256x128 Gram tiles (first 1024 pairs) ---------
// VERBATIM R10 inner structure (43.0 us, 0 conflicts, VGPR 64, no spill).
__global__ __launch_bounds__(512, 4) void gemm_disp_kernel(
    const unsigned char* __restrict__ Phi8, float* __restrict__ rowsum) {
    __shared__ __align__(16) char smem[3 * SLOTB];   // 72 KiB

    // XCD-aware swizzle over exactly 1024 = 8*128 pairs
    int bid = blockIdx.x;
    int u = (bid & 7) * (NFULL / 8) + (bid >> 3);
    int i = 0;
    while (u >= NTJ - 2 * i) { u -= NTJ - 2 * i; ++i; }
    const int j = 2 * i + u;                // j >= 2i
    const bool diagovl = ((j >> 1) == i);

    const int w    = threadIdx.x >> 6;      // wave 0..7
    const int lane = threadIdx.x & 63;
    const int wr = w >> 1, wc = w & 1;      // 4x2 waves, 64x64 each
    const int h = lane >> 4;
    const int r = lane & 15;
    const int rseg = (h ^ ((r >> 1) & 3)) * 16;

    const int Ibase = i * 256, Jbase = j * 128;

    f32x4 acc[4][4];
    #pragma unroll
    for (int m = 0; m < 4; ++m)
        #pragma unroll
        for (int n = 0; n < 4; ++n) acc[m][n] = (f32x4){0.f, 0.f, 0.f, 0.f};

    const int srow = lane >> 2;
    const int sseg = (lane & 3) ^ ((lane >> 3) & 3);
    const unsigned char* gA =
        Phi8 + (size_t)(Ibase + w * 32 + srow) * FEAT + sseg * 16;
    const unsigned char* gB =
        Phi8 + (size_t)(Jbase + w * 16 + srow) * FEAT + sseg * 16;

#define STAGE(s)                                                              \
    {                                                                         \
        char* base = smem + ((s) % 3) * SLOTB;                                \
        __builtin_amdgcn_global_load_lds(                                     \
            (const __attribute__((address_space(1))) void*)(gA + (s) * 64),   \
            (__attribute__((address_space(3))) void*)(base + w * 2048),       \
            16, 0, 0);                                                        \
        __builtin_amdgcn_global_load_lds(                                     \
            (const __attribute__((address_space(1))) void*)(gA + 16 * FEAT + (s) * 64), \
            (__attribute__((address_space(3))) void*)(base + w * 2048 + 1024),\
            16, 0, 0);                                                        \
        __builtin_amdgcn_global_load_lds(                                     \
            (const __attribute__((address_space(1))) void*)(gB + (s) * 64),   \
            (__attribute__((address_space(3))) void*)(base + 16384 + w * 1024),\
            16, 0, 0);                                                        \
    }

#define MF8(ai, bi, mi, ni)                                                   \
    acc[mi][ni] = __builtin_amdgcn_mfma_f32_16x16x32_fp8_fp8(                 \
        ai[0], bi[0], acc[mi][ni], 0, 0, 0);                                  \
    acc[mi][ni] = __builtin_amdgcn_mfma_f32_16x16x32_fp8_fp8(                 \
        ai[1], bi[1], acc[mi][ni], 0, 0, 0);

#define SLOT(s, TAIL)                                                         \
    {                                                                         \
        const char* As = smem + ((s) % 3) * SLOTB;                            \
        const char* Bs = As + 16384;                                          \
        longx2 a0, a1, a2, a3, b0, b1, b2, b3;                                \
        b0 = *(const longx2*)(Bs + (wc * 64 +  0 + r) * 64 + rseg);           \
        b1 = *(const longx2*)(Bs + (wc * 64 + 16 + r) * 64 + rseg);           \
        b2 = *(const longx2*)(Bs + (wc * 64 + 32 + r) * 64 + rseg);           \
        b3 = *(const longx2*)(Bs + (wc * 64 + 48 + r) * 64 + rseg);           \
        a0 = *(const longx2*)(As + (wr * 64 +  0 + r) * 64 + rseg);           \
        a1 = *(const longx2*)(As + (wr * 64 + 16 + r) * 64 + rseg);           \
        a2 = *(const longx2*)(As + (wr * 64 + 32 + r) * 64 + rseg);           \
        a3 = *(const longx2*)(As + (wr * 64 + 48 + r) * 64 + rseg);           \
        __builtin_amdgcn_s_setprio(1);                                        \
        MF8(a0, b0, 0, 0) MF8(a1, b0, 1, 0) MF8(a2, b0, 2, 0) MF8(a3, b0, 3, 0) \
        MF8(a0, b1, 0, 1) MF8(a1, b1, 1, 1) MF8(a2, b1, 2, 1) MF8(a3, b1, 3, 1) \
        MF8(a0, b2, 0, 2) MF8(a1, b2, 1, 2) MF8(a2, b2, 2, 2) MF8(a3, b2, 3, 2) \
        MF8(a0, b3, 0, 3) MF8(a1, b3, 1, 3) MF8(a2, b3, 2, 3) MF8(a3, b3, 3, 3) \
        __builtin_amdgcn_s_setprio(0);                                        \
        TAIL                                                                  \
    }

#define TAIL_MID(s)                                                           \
    STAGE((s) + 2)                                                            \
    asm volatile("s_waitcnt vmcnt(3)" ::: "memory");                          \
    __builtin_amdgcn_s_barrier();
#define TAIL_6                                                                \
    asm volatile("s_waitcnt vmcnt(0)" ::: "memory");                          \
    __builtin_amdgcn_s_barrier();
#define TAIL_7

    STAGE(0) STAGE(1)
    asm volatile("s_waitcnt vmcnt(3)" ::: "memory");
    __builtin_amdgcn_s_barrier();

    SLOT(0, TAIL_MID(0)) SLOT(1, TAIL_MID(1)) SLOT(2, TAIL_MID(2))
    SLOT(3, TAIL_MID(3)) SLOT(4, TAIL_MID(4)) SLOT(5, TAIL_MID(5))
    SLOT(6, TAIL_6)
    SLOT(7, TAIL_7)

    #pragma unroll
    for (int m = 0; m < 4; ++m)
        #pragma unroll
        for (int n = 0; n < 4; ++n)
            #pragma unroll
            for (int q = 0; q < 4; ++q) {
                float v = __expf(acc[m][n][q] * 10.0f);
                if (diagovl &&
                    (Ibase + wr * 64 + m * 16 + h * 4 + q) ==
                    (Jbase + wc * 64 + n * 16 + r))
                    v = 0.f;
                acc[m][n][q] = v;
            }

    #pragma unroll
    for (int m = 0; m < 4; ++m) {
        float rs[4];
        #pragma unroll
        for (int q = 0; q < 4; ++q)
            rs[q] = acc[m][0][q] + acc[m][1][q] + acc[m][2][q] + acc[m][3][q];
        #pragma unroll
        for (int q = 0; q < 4; ++q)
            #pragma unroll
            for (int off = 1; off < 16; off <<= 1) rs[q] += __shfl_xor(rs[q], off);
        if (r == 0) {
            #pragma unroll
            for (int q = 0; q < 4; ++q)
                atomicAdd(&rowsum[Ibase + wr * 64 + m * 16 + h * 4 + q], rs[q]);
        }
    }

    if (!diagovl) {
        #pragma unroll
        for (int n = 0; n < 4; ++n) {
            float cs = 0.f;
            #pragma unroll
            for (int m = 0; m < 4; ++m)
                #pragma unroll
                for (int q = 0; q < 4; ++q) cs += acc[m][n][q];
            cs += __shfl_xor(cs, 16);
            cs += __shfl_xor(cs, 32);
            if (lane < 16)
                atomicAdd(&rowsum[Jbase + wc * 64 + n * 16 + r], cs);
        }
    }
}

// ---------------- Kernel 2b: remaining 32 pairs as 128 quarter-blocks ------
// 64-row x 128-col quarters (4 waves of 64x32, acc[4][2]); same ring-3
// schedule, swizzle constants, and credit scheme. Last block computes loss.
__global__ __launch_bounds__(256, 4) void gemm_rem_kernel(
    const unsigned char* __restrict__ Phi8, float* __restrict__ rowsum,
    int* __restrict__ done, float* __restrict__ out) {
    __shared__ __align__(16) char smem[3 * SLOTB_R]; // 36 KiB

    const int p  = NFULL + (blockIdx.x & 31);
    const int qt = blockIdx.x >> 5;         // quarter 0..3
    int u = p, i = 0;
    while (u >= NTJ - 2 * i) { u -= NTJ - 2 * i; ++i; }
    const int j = 2 * i + u;
    const bool diagovl = ((j >> 1) == i);

    const int w    = threadIdx.x >> 6;      // wave 0..3 (owns cols w*32..+32)
    const int lane = threadIdx.x & 63;
    const int h = lane >> 4;
    const int r = lane & 15;
    const int rseg = (h ^ ((r >> 1) & 3)) * 16;

    const int Ibase = i * 256 + qt * 64, Jbase = j * 128;

    f32x4 acc[4][2];
    #pragma unroll
    for (int m = 0; m < 4; ++m)
        #pragma unroll
        for (int n = 0; n < 2; ++n) acc[m][n] = (f32x4){0.f, 0.f, 0.f, 0.f};

    // staging: 3 loads/wave/slot. A (4 KB): rows w*16+srow; B (8 KB): rows
    // w*32+{0,16}+srow. Same source pre-swizzle as the full kernel.
    const int srow = lane >> 2;
    const int sseg = (lane & 3) ^ ((lane >> 3) & 3);
    const unsigned char* gA =
        Phi8 + (size_t)(Ibase + w * 16 + srow) * FEAT + sseg * 16;
    const unsigned char* gB =
        Phi8 + (size_t)(Jbase + w * 32 + srow) * FEAT + sseg * 16;

#define STAGE_R(s)                                                            \
    {                                                                         \
        char* base = smem + ((s) % 3) * SLOTB_R;                              \
        __builtin_amdgcn_global_load_lds(                                     \
            (const __attribute__((address_space(1))) void*)(gA + (s) * 64),   \
            (__attribute__((address_space(3))) void*)(base + w * 1024),       \
            16, 0, 0);                                                        \
        __builtin_amdgcn_global_load_lds(                                     \
            (const __attribute__((address_space(1))) void*)(gB + (s) * 64),   \
            (__attribute__((address_space(3))) void*)(base + 4096 + w * 2048),\
            16, 0, 0);                                                        \
        __builtin_amdgcn_global_load_lds(                                     \
            (const __attribute__((address_space(1))) void*)(gB + 16 * FEAT + (s) * 64), \
            (__attribute__((address_space(3))) void*)(base + 4096 + w * 2048 + 1024), \
            16, 0, 0);                                                        \
    }

#define SLOT_R(s, TAIL)                                                       \
    {                                                                         \
        const char* As = smem + ((s) % 3) * SLOTB_R;                          \
        const char* Bs = As + 4096;                                           \
        longx2 a0, a1, a2, a3, b0, b1;                                        \
        b0 = *(const longx2*)(Bs + (w * 32 +  0 + r) * 64 + rseg);            \
        b1 = *(const longx2*)(Bs + (w * 32 + 16 + r) * 64 + rseg);            \
        a0 = *(const longx2*)(As + ( 0 + r) * 64 + rseg);                     \
        a1 = *(const longx2*)(As + (16 + r) * 64 + rseg);                     \
        a2 = *(const longx2*)(As + (32 + r) * 64 + rseg);                     \
        a3 = *(const longx2*)(As + (48 + r) * 64 + rseg);                     \
        __builtin_amdgcn_s_setprio(1);                                        \
        MF8(a0, b0, 0, 0) MF8(a1, b0, 1, 0) MF8(a2, b0, 2, 0) MF8(a3, b0, 3, 0) \
        MF8(a0, b1, 0, 1) MF8(a1, b1, 1, 1) MF8(a2, b1, 2, 1) MF8(a3, b1, 3, 1) \
        __builtin_amdgcn_s_setprio(0);                                        \
        TAIL                                                                  \
    }

#define TAIL_MID_R(s)                                                         \
    STAGE_R((s) + 2)                                                          \
    asm volatile("s_waitcnt vmcnt(3)" ::: "memory");                          \
    __builtin_amdgcn_s_barrier();

    STAGE_R(0) STAGE_R(1)
    asm volatile("s_waitcnt vmcnt(3)" ::: "memory");
    __builtin_amdgcn_s_barrier();

    SLOT_R(0, TAIL_MID_R(0)) SLOT_R(1, TAIL_MID_R(1)) SLOT_R(2, TAIL_MID_R(2))
    SLOT_R(3, TAIL_MID_R(3)) SLOT_R(4, TAIL_MID_R(4)) SLOT_R(5, TAIL_MID_R(5))
    SLOT_R(6, TAIL_6)
    SLOT_R(7, TAIL_7)

    // epilogue
    #pragma unroll
    for (int m = 0; m < 4; ++m)
        #pragma unroll
        for (int n = 0; n < 2; ++n)
            #pragma unroll
            for (int q = 0; q < 4; ++q) {
                float v = __expf(acc[m][n][q] * 10.0f);
                if ((Ibase + m * 16 + h * 4 + q) == (Jbase + w * 32 + n * 16 + r))
                    v = 0.f;                 // true diagonal only
                acc[m][n][q] = v;
            }

    #pragma unroll
    for (int m = 0; m < 4; ++m) {
        float rs[4];
        #pragma unroll
        for (int q = 0; q < 4; ++q)
            rs[q] = acc[m][0][q] + acc[m][1][q];
        #pragma unroll
        for (int q = 0; q < 4; ++q)
            #pragma unroll
            for (int off = 1; off < 16; off <<= 1) rs[q] += __shfl_xor(rs[q], off);
        if (r == 0) {
            #pragma unroll
            for (int q = 0; q < 4; ++q)
                atomicAdd(&rowsum[Ibase + m * 16 + h * 4 + q], rs[q]);
        }
    }

    if (!diagovl) {
        #pragma unroll
        for (int n = 0; n < 2; ++n) {
            float cs = 0.f;
            #pragma unroll
            for (int m = 0; m < 4; ++m)
                #pragma unroll
                for (int q = 0; q < 4; ++q) cs += acc[m][n][q];
            cs += __shfl_xor(cs, 16);
            cs += __shfl_xor(cs, 32);
            if (lane < 16)
                atomicAdd(&rowsum[Jbase + w * 32 + n * 16 + r], cs);
        }
    }

    // fused loss: last of the 128 rem blocks (full kernel already complete
    // by stream order) reduces rowsum -> out.
    __threadfence();
    __shared__ int islast;
    __shared__ float red[4];
    if (threadIdx.x == 0) islast = (atomicAdd(done, 1) == 127) ? 1 : 0;
    __syncthreads();
    if (islast) {
        float s = 0.f;
        for (int idx = threadIdx.x; idx < N_CLS; idx += 256) {
            float v = atomicAdd(&rowsum[idx], 0.0f);   // device-scope read
            s += logf(v * (1.0f / (float)(N_CLS - 1)));
        }
        #pragma unroll
        for (int off = 32; off; off >>= 1) s += __shfl_xor(s, off);
        if (lane == 0) red[threadIdx.x >> 6] = s;
        __syncthreads();
        if (threadIdx.x == 0)
            out[0] = (red[0] + red[1] + red[2] + red[3]) * (1.0f / (float)N_CLS);
    }
}

extern "C" void kernel_launch(void* const* d_in, const int* in_sizes, int n_in,
                              void* d_out, int out_size, void* d_ws, size_t ws_size,
                              hipStream_t stream) {
    (void)in_sizes; (void)n_in; (void)out_size; (void)ws_size;
    const float* features = (const float*)d_in[0];
    const int*   labels   = (const int*)d_in[1];
    const float* protos   = (const float*)d_in[2];
    float* out = (float*)d_out;

    unsigned char* Phi8 = (unsigned char*)d_ws;                     // 4 MiB
    float* rowsum = (float*)(Phi8 + (size_t)N_CLS * FEAT);          // 32 KiB
    int* done = (int*)(rowsum + N_CLS);

    ema_kernel<<<N_CLS / 4, 256, 0, stream>>>(features, labels, protos, Phi8,
                                              rowsum, done);
    gemm_disp_kernel<<<NFULL, 512, 0, stream>>>(Phi8, rowsum);
    gemm_rem_kernel<<<NREMP * 4, 256, 0, stream>>>(Phi8, rowsum, done, out);
}